// Round 1
// baseline (214.165 us; speedup 1.0000x reference)
//
#include <hip/hip_runtime.h>

#define HW 256
#define CH 64

__global__ __launch_bounds__(256) void DeformableConvLayer_kernel(
    const float* __restrict__ inp,    // [4,256,256,64]
    const float* __restrict__ gt,     // [256,256]
    const float* __restrict__ off,    // [4,256,256,18]
    const float* __restrict__ ker,    // [3,3,64] -> [9][64]
    const float* __restrict__ bias,   // [1]
    float* __restrict__ out)          // [4,256,256]
{
    int p = blockIdx.x * 256 + threadIdx.x;     // 0 .. 262143
    int b = p >> 16;
    int i = (p >> 8) & 255;
    int j = p & 255;

    const float* offp = off + (long)p * 18;
    const float* inb  = inp + (long)b * (HW * HW * CH);

    float acc = 0.f;

    #pragma unroll
    for (int ky = 0; ky < 3; ++ky) {
        #pragma unroll
        for (int kx = 0; kx < 3; ++kx) {
            const int tap = ky * 3 + kx;

            // --- base patch coords, replicating zero-padded index grid:
            // interior iff (i+ky-1) in [0,255] AND (j+kx-1) in [0,255]; else (0,0)
            int iy = i + ky - 1;
            int ix = j + kx - 1;
            bool interior = (iy >= 0) & (iy < HW) & (ix >= 0) & (ix < HW);
            int yi = interior ? iy : 0;
            int xi = interior ? ix : 0;

            // p_mask = padded_mask[yi, xi] (padded mask: zero ring at index 0)
            float p_mask = (yi >= 1 && xi >= 1) ? gt[(yi - 1) * HW + (xi - 1)] : 0.f;

            // offsets: [..., tap, {y,x}]
            float2 o2 = *(const float2*)(offp + 2 * tap);
            float y_off = o2.x, x_off = o2.y;
            float yf = (float)yi, xf = (float)xi;

            // mask at floored offset point, coords clipped to [0, 257]
            float yof = fminf(fmaxf(floorf(yf + y_off), 0.f), 257.f);
            float xof = fminf(fmaxf(floorf(xf + x_off), 0.f), 257.f);
            int yo = (int)yof, xo = (int)xof;
            float p_mask_off = (yo >= 1 && yo <= HW && xo >= 1 && xo <= HW)
                               ? gt[(yo - 1) * HW + (xo - 1)] : 0.f;
            float diff = (p_mask != p_mask_off) ? 1.f : 0.f;

            // final sample coords, clipped to [0, 255]; sample PADDED input
            float y = fminf(fmaxf(yf + y_off * diff, 0.f), 255.f);
            float x = fminf(fmaxf(xf + x_off * diff, 0.f), 255.f);
            int y0 = (int)y;   // y >= 0, trunc == floor
            int x0 = (int)x;

            // padded input: index 0 in either dim reads the zero ring
            bool valid = (y0 >= 1) & (x0 >= 1);
            float s = valid ? 1.f : 0.f;
            const float* src = inb + (valid ? (((y0 - 1) * HW + (x0 - 1)) * CH) : 0);
            const float* wp  = ker + tap * CH;

            float tacc = 0.f;
            #pragma unroll
            for (int c = 0; c < CH; c += 4) {
                float4 v = *(const float4*)(src + c);
                float4 w = *(const float4*)(wp + c);
                tacc += v.x * w.x + v.y * w.y + v.z * w.z + v.w * w.w;
            }
            acc = fmaf(s, tacc, acc);
        }
    }

    out[p] = acc + bias[0];
}

extern "C" void kernel_launch(void* const* d_in, const int* in_sizes, int n_in,
                              void* d_out, int out_size, void* d_ws, size_t ws_size,
                              hipStream_t stream) {
    const float* inp  = (const float*)d_in[0];
    const float* gt   = (const float*)d_in[1];
    const float* off  = (const float*)d_in[2];
    const float* ker  = (const float*)d_in[3];
    const float* bias = (const float*)d_in[4];
    float* out = (float*)d_out;

    // 4*256*256 = 262144 pixels, 256 threads each -> 1024 blocks
    DeformableConvLayer_kernel<<<1024, 256, 0, stream>>>(inp, gt, off, ker, bias, out);
}

// Round 2
// 194.845 us; speedup vs baseline: 1.0992x; 1.0992x over previous
//
#include <hip/hip_runtime.h>

#define HW 256
#define CH 64

// Layout: 256 threads/block = 4 waves; each wave handles 4 pixels
// (16 lanes per pixel: lane%16 = float4 channel-chunk, lane/16 = pixel).
// Tap gather per pixel = 16 lanes x 16B = one contiguous 256B segment.
__global__ __launch_bounds__(256) void DeformableConvLayer_kernel(
    const float* __restrict__ inp,    // [4,256,256,64]
    const float* __restrict__ gt,     // [256,256]
    const float* __restrict__ off,    // [4,256,256,18]
    const float* __restrict__ ker,    // [9][64]
    const float* __restrict__ bias,   // [1]
    float* __restrict__ out)          // [4,256,256]
{
    const int lane = threadIdx.x & 63;
    const int wave = threadIdx.x >> 6;
    const int q    = lane >> 4;       // pixel-in-wave 0..3
    const int t    = lane & 15;       // channel quad 0..15

    // XCD swizzle: 16384 blocks; give each XCD a contiguous chunk of 2048
    // blocks (= 128 contiguous image rows) so its L2 streams ~8 MB instead
    // of striding the whole input.
    const int bid  = blockIdx.x;
    const int vb   = (bid & 7) * 2048 + (bid >> 3);

    const int p = vb * 16 + wave * 4 + q;   // pixel id 0..262143
    const int b = p >> 16;
    const int i = (p >> 8) & 255;
    const int j = p & 255;

    const float* offp = off + (long)p * 18;
    const float* inb  = inp + (long)b * (HW * HW * CH);

    float acc = 0.f;

    #pragma unroll
    for (int tap = 0; tap < 9; ++tap) {
        const int ky = tap / 3, kx = tap % 3;

        // base patch coords with zero-pad index-grid semantics
        int iy = i + ky - 1;
        int ix = j + kx - 1;
        bool interior = (iy >= 0) & (iy < HW) & (ix >= 0) & (ix < HW);
        int yi = interior ? iy : 0;
        int xi = interior ? ix : 0;

        float p_mask = (yi >= 1 && xi >= 1) ? gt[(yi - 1) * HW + (xi - 1)] : 0.f;

        float2 o2 = *(const float2*)(offp + 2 * tap);
        float y_off = o2.x, x_off = o2.y;
        float yf = (float)yi, xf = (float)xi;

        float yof = fminf(fmaxf(floorf(yf + y_off), 0.f), 257.f);
        float xof = fminf(fmaxf(floorf(xf + x_off), 0.f), 257.f);
        int yo = (int)yof, xo = (int)xof;
        float p_mask_off = (yo >= 1 && yo <= HW && xo >= 1 && xo <= HW)
                           ? gt[(yo - 1) * HW + (xo - 1)] : 0.f;
        float diff = (p_mask != p_mask_off) ? 1.f : 0.f;

        float y = fminf(fmaxf(yf + y_off * diff, 0.f), 255.f);
        float x = fminf(fmaxf(xf + x_off * diff, 0.f), 255.f);
        int y0 = (int)y;
        int x0 = (int)x;

        bool valid = (y0 >= 1) & (x0 >= 1);
        float s = valid ? 1.f : 0.f;
        const float* src = inb + (valid ? (((y0 - 1) * HW + (x0 - 1)) * CH) : 0);

        float4 v = *(const float4*)(src + t * 4);
        float4 w = *(const float4*)(ker + tap * CH + t * 4);
        float d = v.x * w.x + v.y * w.y + v.z * w.z + v.w * w.w;
        acc = fmaf(s, d, acc);
    }

    // reduce the 16 channel-quads of this pixel (lane bits 0..3)
    acc += __shfl_xor(acc, 8);
    acc += __shfl_xor(acc, 4);
    acc += __shfl_xor(acc, 2);
    acc += __shfl_xor(acc, 1);

    if (t == 0) out[p] = acc + bias[0];
}

extern "C" void kernel_launch(void* const* d_in, const int* in_sizes, int n_in,
                              void* d_out, int out_size, void* d_ws, size_t ws_size,
                              hipStream_t stream) {
    const float* inp  = (const float*)d_in[0];
    const float* gt   = (const float*)d_in[1];
    const float* off  = (const float*)d_in[2];
    const float* ker  = (const float*)d_in[3];
    const float* bias = (const float*)d_in[4];
    float* out = (float*)d_out;

    // 262144 pixels / 16 per block = 16384 blocks
    DeformableConvLayer_kernel<<<16384, 256, 0, stream>>>(inp, gt, off, ker, bias, out);
}

// Round 3
// 133.083 us; speedup vs baseline: 1.6093x; 1.4641x over previous
//
#include <hip/hip_runtime.h>

#define HW 256
#define CH 64

// 256 threads = 4 waves; each wave handles 4 pixels (16 lanes/pixel:
// lane%16 = channel quad, lane/16 = pixel-in-wave).
// Phase 1: lanes t=0..8 of each group compute ONE tap's sample address.
// Phase 2: broadcast addresses via shuffle.
// Phase 3: all 9 input gathers issued independently (latency batched).
// Phase 4: FMA against LDS-staged weights, 4-step shuffle reduce, store.
__global__ __launch_bounds__(256, 6) void DeformableConvLayer_kernel(
    const float* __restrict__ inp,    // [4,256,256,64]
    const float* __restrict__ gt,     // [256,256]
    const float* __restrict__ off,    // [4,256,256,18]
    const float* __restrict__ ker,    // [9][64]
    const float* __restrict__ bias,   // [1]
    float* __restrict__ out)          // [4,256,256]
{
    __shared__ float wlds[576];       // 9 taps x 64 ch
    const int tid = threadIdx.x;
    if (tid < 144) ((float4*)wlds)[tid] = ((const float4*)ker)[tid];

    const int lane = tid & 63;
    const int wave = tid >> 6;
    const int q16  = lane & 48;       // pixel-in-wave * 16
    const int t    = lane & 15;       // channel quad

    // XCD swizzle: contiguous 2048-block chunk per XCD
    const int bid = blockIdx.x;
    const int vb  = (bid & 7) * 2048 + (bid >> 3);

    const int p = vb * 16 + wave * 4 + (q16 >> 4);
    const int b = p >> 16;
    const int i = (p >> 8) & 255;
    const int j = p & 255;
    const float* inb = inp + (long)b * (HW * HW * CH);

    // ---- Phase 1: one tap per lane (t<9) ----
    int pack = 0;
    if (t < 9) {
        const int tap = t;
        const int ky = tap / 3, kx = tap - ky * 3;
        int iy = i + ky - 1, ix = j + kx - 1;
        bool interior = (iy >= 0) & (iy < HW) & (ix >= 0) & (ix < HW);
        int yi = interior ? iy : 0;
        int xi = interior ? ix : 0;

        float p_mask = (yi >= 1 && xi >= 1) ? gt[(yi - 1) * HW + (xi - 1)] : 0.f;

        float2 o2 = *(const float2*)(off + (long)p * 18 + 2 * tap);
        float yf = (float)yi, xf = (float)xi;

        float yof = fminf(fmaxf(floorf(yf + o2.x), 0.f), 257.f);
        float xof = fminf(fmaxf(floorf(xf + o2.y), 0.f), 257.f);
        int yo = (int)yof, xo = (int)xof;
        float p_mask_off = (yo >= 1 && yo <= HW && xo >= 1 && xo <= HW)
                           ? gt[(yo - 1) * HW + (xo - 1)] : 0.f;
        float diff = (p_mask != p_mask_off) ? 1.f : 0.f;

        float y = fminf(fmaxf(yf + o2.x * diff, 0.f), 255.f);
        float x = fminf(fmaxf(xf + o2.y * diff, 0.f), 255.f);
        int y0 = (int)y;
        int x0 = (int)x;

        bool valid = (y0 >= 1) & (x0 >= 1);
        int eoff = ((y0 - 1) * HW + (x0 - 1)) * CH;
        pack = valid ? eoff : -1;     // sign bit = invalid (zero ring)
    }

    // ---- Phase 2: broadcast tap addresses to all 16 lanes of the group ----
    int pk[9];
    #pragma unroll
    for (int k = 0; k < 9; ++k) pk[k] = __shfl(pack, q16 + k);

    // ---- Phase 3: batched independent gathers (36 VGPRs in flight) ----
    float4 v[9];
    #pragma unroll
    for (int k = 0; k < 9; ++k) {
        int eo = pk[k] >= 0 ? pk[k] : 0;
        v[k] = *(const float4*)(inb + eo + t * 4);
    }

    __syncthreads();                  // weights staged

    // ---- Phase 4: FMA + reduce ----
    float acc = 0.f;
    #pragma unroll
    for (int k = 0; k < 9; ++k) {
        float s = pk[k] >= 0 ? 1.f : 0.f;
        float4 w = ((const float4*)wlds)[k * 16 + t];
        float d = v[k].x * w.x + v[k].y * w.y + v[k].z * w.z + v[k].w * w.w;
        acc = fmaf(s, d, acc);
    }

    acc += __shfl_xor(acc, 8);
    acc += __shfl_xor(acc, 4);
    acc += __shfl_xor(acc, 2);
    acc += __shfl_xor(acc, 1);
    if (t == 0) out[p] = acc + bias[0];
}

extern "C" void kernel_launch(void* const* d_in, const int* in_sizes, int n_in,
                              void* d_out, int out_size, void* d_ws, size_t ws_size,
                              hipStream_t stream) {
    const float* inp  = (const float*)d_in[0];
    const float* gt   = (const float*)d_in[1];
    const float* off  = (const float*)d_in[2];
    const float* ker  = (const float*)d_in[3];
    const float* bias = (const float*)d_in[4];
    float* out = (float*)d_out;

    // 262144 pixels / 16 per block = 16384 blocks
    DeformableConvLayer_kernel<<<16384, 256, 0, stream>>>(inp, gt, off, ker, bias, out);
}